// Round 13
// baseline (532.815 us; speedup 1.0000x reference)
//
#include <hip/hip_runtime.h>
#include <hip/hip_bf16.h>

#define BATCH 16
#define CINC 96
#define HGT 112
#define WID 112
#define HW 12544          // 112*112
#define C1N 192
#define C2N 384
#define EPSV 1e-5f

typedef _Float16 f16x8 __attribute__((ext_vector_type(8)));
typedef _Float16 f16x4 __attribute__((ext_vector_type(4)));
typedef float    f32x4 __attribute__((ext_vector_type(4)));

// d_ws layout (float offsets unless noted)
#define WS_S      0        // 16*96 f32 h-sums (zeroed each launch)
#define WS_A1B1   1536     // 16*192 f32
#define WS_W1F    4608     // 192*3
#define WS_B1F    5184     // 192
#define WS_W2F    5376     // 384*3
#define WS_B2F    6528     // 384
#define WS_S3     6912     // 96
#define WS_B3     7008     // 96
#define WS_WPF_BYTES (7104*4)                    // f16 wpf[ksg][rt][lane][8]
#define WS_H_BYTES   (WS_WPF_BYTES + CINC*C2N*2) // f16 h[16][96][12544] = 38.5 MB

// ---------------- prep: fold BN into weights; Wp -> k-step-contiguous fragments
// wpf[((ksg*6+rt)*64+lane)*8+e] = Wp[rt*16+(lane&15)][ksg*32+(lane>>4)*8+e]
// Wp[m][k] = w_pw[m][(k%64)*6 + k/64]  (channel shuffle groups=6 folded)
__global__ void k_prep(const float* __restrict__ wdw1, const float* __restrict__ g1,
                       const float* __restrict__ bb1, const float* __restrict__ m1,
                       const float* __restrict__ v1,
                       const float* __restrict__ wdw2, const float* __restrict__ g2,
                       const float* __restrict__ bb2, const float* __restrict__ m2,
                       const float* __restrict__ v2,
                       const float* __restrict__ wpw, const float* __restrict__ g3,
                       const float* __restrict__ bb3, const float* __restrict__ m3,
                       const float* __restrict__ v3,
                       float* ws)
{
    int t = blockIdx.x * blockDim.x + threadIdx.x;
    int stride = gridDim.x * blockDim.x;
    float* w1f = ws + WS_W1F; float* b1f = ws + WS_B1F;
    float* w2f = ws + WS_W2F; float* b2f = ws + WS_B2F;
    float* s3  = ws + WS_S3;  float* b3f = ws + WS_B3;
    _Float16* wpf = (_Float16*)((char*)ws + WS_WPF_BYTES);

    for (int c = t; c < C1N; c += stride) {
        float s = g1[c] / sqrtf(v1[c] + EPSV);
        w1f[c*3+0] = wdw1[c*3+0] * s;
        w1f[c*3+1] = wdw1[c*3+1] * s;
        w1f[c*3+2] = wdw1[c*3+2] * s;
        b1f[c] = bb1[c] - m1[c] * s;
    }
    for (int c = t; c < C2N; c += stride) {
        float s = g2[c] / sqrtf(v2[c] + EPSV);
        w2f[c*3+0] = wdw2[c*3+0] * s;
        w2f[c*3+1] = wdw2[c*3+1] * s;
        w2f[c*3+2] = wdw2[c*3+2] * s;
        b2f[c] = bb2[c] - m2[c] * s;
    }
    for (int c = t; c < CINC; c += stride) {
        float s = g3[c] / sqrtf(v3[c] + EPSV);
        s3[c] = s; b3f[c] = bb3[c] - m3[c] * s;
    }
    for (int idx = t; idx < CINC * C2N; idx += stride) {
        int e = idx & 7;
        int l2 = idx >> 3;
        int lane = l2 & 63;
        int l3 = l2 >> 6;
        int rt = l3 % 6, ksg = l3 / 6;
        int m = rt * 16 + (lane & 15);
        int k = ksg * 32 + (lane >> 4) * 8 + e;
        int o = (k & 63) * 6 + (k >> 6);
        wpf[idx] = (_Float16)wpw[m * C2N + o];
    }
}

// ---------------- dw-conv for one channel: 4 cols per thread, shfl horizontals --
__device__ __forceinline__ void dw_channel(
    const f32x4 top, const f32x4 mid, const f32x4 bot,
    float eT, float eM, float eB,
    bool ymok, bool ypok, bool ev, int lane, int c4,
    float wa0, float wa1, float wa2, float ba,
    float wb0, float wb1, float wb2, float bb,
    const float* __restrict__ w2f, const float* __restrict__ b2f, int c2b,
    f16x4 uv[4])
{
    float va[4], vb[4];
    #pragma unroll
    for (int j = 0; j < 4; ++j) {
        float tt = ymok ? top[j] : 0.f;
        float bt = ypok ? bot[j] : 0.f;
        va[j] = fmaf(wa0, tt, fmaf(wa1, mid[j], fmaf(wa2, bt, ba)));
        vb[j] = fmaf(wb0, tt, fmaf(wb1, mid[j], fmaf(wb2, bt, bb)));
    }
    // conv2 zero-pads BN1 output: out-of-image edge column contributes 0
    float etS = (ymok && ev) ? eT : 0.f;
    float ebS = (ypok && ev) ? eB : 0.f;
    float emS = ev ? eM : 0.f;
    float vea = ev ? fmaf(wa0, etS, fmaf(wa1, emS, fmaf(wa2, ebS, ba))) : 0.f;
    float veb = ev ? fmaf(wb0, etS, fmaf(wb1, emS, fmaf(wb2, ebS, bb))) : 0.f;

    float vLa = __shfl(va[3], (lane + 63) & 63);
    float vLb = __shfl(vb[3], (lane + 63) & 63);
    float vRa = __shfl(va[0], (lane + 1) & 63);
    float vRb = __shfl(vb[0], (lane + 1) & 63);
    if (c4 == 0)  { vLa = vea; vLb = veb; }
    if (c4 == 15) { vRa = vea; vRb = veb; }

    float pa[6] = {vLa, va[0], va[1], va[2], va[3], vRa};
    float pb[6] = {vLb, vb[0], vb[1], vb[2], vb[3], vRb};
    #pragma unroll
    for (int j = 0; j < 4; ++j) {
        #pragma unroll
        for (int jj = 0; jj < 4; ++jj) {
            float p0 = (jj < 2) ? pa[j]     : pb[j];
            float p1 = (jj < 2) ? pa[j + 1] : pb[j + 1];
            float p2 = (jj < 2) ? pa[j + 2] : pb[j + 2];
            float tv = fmaf(w2f[(c2b+jj)*3+0], p0,
                       fmaf(w2f[(c2b+jj)*3+1], p1,
                       fmaf(w2f[(c2b+jj)*3+2], p2, b2f[c2b+jj])));
            uv[j][jj] = (_Float16)fminf(fmaxf(tv, 0.f), 6.f);
        }
    }
}

// ---------------- main: 12 x (prefetched gather(32k) -> 1-kstep MFMA) -> h+sums
// block = 4 rows x 64 cols; LDS 27 KB -> high blocks/CU; reads conflict-free
__global__ __launch_bounds__(256, 6) void k_main7(const float* __restrict__ x,
                                                  const float* __restrict__ ws,
                                                  float* __restrict__ sums,
                                                  _Float16* __restrict__ h_out)
{
    __shared__ __align__(16) char smem[26624];   // u: [0,20480) pos*80+s*16; wpf: [20480,26624)
    __shared__ float ssum[CINC];

    int t   = threadIdx.x;
    int bid = blockIdx.x;
    int logical = (bid & 7) * 112 + (bid >> 3);   // XCD-chunked (896 = 8*112)
    int b   = logical / 56;
    int rem = logical - b * 56;
    int y0  = (rem >> 1) * 4;
    int x0  = (rem & 1) * 48;

    int wv = t >> 6, lane = t & 63;
    int r = lane >> 4, c4 = lane & 15;
    int gy = y0 + r;
    int gc = x0 + 4 * c4;
    int col16 = c4, g = r;

    const float* w1f = ws + WS_W1F; const float* b1f = ws + WS_B1F;
    const float* w2f = ws + WS_W2F; const float* b2f = ws + WS_B2F;

    if (t < CINC) ssum[t] = 0.f;

    bool ymok = gy >= 1;
    bool ypok = gy + 1 < HGT;
    bool isE  = (c4 == 0) | (c4 == 15);
    int  ecol = (c4 == 0) ? (x0 - 1) : (x0 + 64);
    bool ev   = isE && ((unsigned)ecol < (unsigned)WID);
    int  secol = ev ? ecol : 0;
    int  tm = ymok ? -WID : 0;
    int  tp = ypok ?  WID : 0;

    f32x4 acc[6][4];
    #pragma unroll
    for (int rt = 0; rt < 6; ++rt)
        #pragma unroll
        for (int ct = 0; ct < 4; ++ct) acc[rt][ct] = (f32x4){0.f, 0.f, 0.f, 0.f};

    f16x8* wpf_s = (f16x8*)(smem + 20480);
    const f16x8* wpf_g = (const f16x8*)((const char*)ws + WS_WPF_BYTES);
    long xb = (long)b * CINC * HW;
    const float* xwave = x + xb + (long)(wv * 2) * HW + (long)gy * WID;  // + chunk*8*HW + col

    // ---- prefetch chunk 0 ----
    f32x4 nT0, nM0, nB0, nT1, nM1, nB1;
    float neT0 = 0.f, neM0 = 0.f, neB0 = 0.f, neT1 = 0.f, neM1 = 0.f, neB1 = 0.f;
    f16x8 nw0, nw1;
    {
        const float* p0 = xwave + gc;
        const float* p1 = p0 + HW;
        nM0 = *(const f32x4*)p0; nT0 = *(const f32x4*)(p0 + tm); nB0 = *(const f32x4*)(p0 + tp);
        nM1 = *(const f32x4*)p1; nT1 = *(const f32x4*)(p1 + tm); nB1 = *(const f32x4*)(p1 + tp);
        if (isE) {
            const float* e0 = xwave + secol;
            const float* e1 = e0 + HW;
            neM0 = e0[0]; neT0 = e0[tm]; neB0 = e0[tp];
            neM1 = e1[0]; neT1 = e1[tm]; neB1 = e1[tp];
        }
        nw0 = wpf_g[t];
        nw1 = nw0;
        if (t < 128) nw1 = wpf_g[256 + t];
    }

    char* ub0 = smem + (r * 64 + 4 * c4) * 80 + wv * 16;

    for (int chunk = 0; chunk < 12; ++chunk) {
        // stage this chunk's Wp fragments (prev MFMA done per trailing barrier)
        wpf_s[t] = nw0;
        if (t < 128) wpf_s[256 + t] = nw1;

        // consume prefetched x
        f32x4 cT0 = nT0, cM0 = nM0, cB0 = nB0, cT1 = nT1, cM1 = nM1, cB1 = nB1;
        float ceT0 = neT0, ceM0 = neM0, ceB0 = neB0, ceT1 = neT1, ceM1 = neM1, ceB1 = neB1;

        // issue next chunk's prefetch (hides under compute + MFMA + barriers)
        if (chunk < 11) {
            long coff = (long)(chunk + 1) * (8 * HW);
            const float* p0 = xwave + coff + gc;
            const float* p1 = p0 + HW;
            nM0 = *(const f32x4*)p0; nT0 = *(const f32x4*)(p0 + tm); nB0 = *(const f32x4*)(p0 + tp);
            nM1 = *(const f32x4*)p1; nT1 = *(const f32x4*)(p1 + tm); nB1 = *(const f32x4*)(p1 + tp);
            if (isE) {
                const float* e0 = xwave + coff + secol;
                const float* e1 = e0 + HW;
                neM0 = e0[0]; neT0 = e0[tm]; neB0 = e0[tp];
                neM1 = e1[0]; neT1 = e1[tm]; neB1 = e1[tp];
            }
            nw0 = wpf_g[(chunk + 1) * 384 + t];
            if (t < 128) nw1 = wpf_g[(chunk + 1) * 384 + 256 + t];
        }

        // compute u for this wave's 2 channels
        int cu0 = __builtin_amdgcn_readfirstlane(chunk * 8 + wv * 2);
        int c1a = cu0 * 2;
        f16x4 uv0[4], uv1[4];
        dw_channel(cT0, cM0, cB0, ceT0, ceM0, ceB0, ymok, ypok, ev, lane, c4,
                   w1f[c1a*3+0], w1f[c1a*3+1], w1f[c1a*3+2], b1f[c1a],
                   w1f[c1a*3+3], w1f[c1a*3+4], w1f[c1a*3+5], b1f[c1a+1],
                   w2f, b2f, cu0 * 4, uv0);
        dw_channel(cT1, cM1, cB1, ceT1, ceM1, ceB1, ymok, ypok, ev, lane, c4,
                   w1f[(c1a+2)*3+0], w1f[(c1a+2)*3+1], w1f[(c1a+2)*3+2], b1f[c1a+2],
                   w1f[(c1a+2)*3+3], w1f[(c1a+2)*3+4], w1f[(c1a+2)*3+5], b1f[c1a+3],
                   w2f, b2f, (cu0 + 1) * 4, uv1);
        #pragma unroll
        for (int j = 0; j < 4; ++j) {
            f16x8 w = __builtin_shufflevector(uv0[j], uv1[j], 0, 1, 2, 3, 4, 5, 6, 7);
            *(f16x8*)(ub0 + j * 80) = w;
        }
        __syncthreads();   // u + wpf ready

        // MFMA: 1 k-step, 6 rt x 4 ct
        f16x8 bfr[4];
        #pragma unroll
        for (int ct = 0; ct < 4; ++ct)
            bfr[ct] = *(const f16x8*)(smem + (wv * 64 + ct * 16 + col16) * 80 + g * 16);
        #pragma unroll
        for (int rt = 0; rt < 6; ++rt) {
            f16x8 afr = wpf_s[rt * 64 + lane];
            #pragma unroll
            for (int ct = 0; ct < 4; ++ct)
                acc[rt][ct] = __builtin_amdgcn_mfma_f32_16x16x32_f16(afr, bfr[ct], acc[rt][ct], 0, 0, 0);
        }
        __syncthreads();   // reads done before next chunk overwrites
    }

    // ---- epilogue: bn3 -> h (f16) in two 48-channel LDS passes -> stores+sums --
    _Float16* h_s = (_Float16*)smem;   // [48][264]
    const float* s3  = ws + WS_S3;
    const float* b3f = ws + WS_B3;
    #pragma unroll
    for (int pass = 0; pass < 2; ++pass) {
        #pragma unroll
        for (int rt3 = 0; rt3 < 3; ++rt3) {
            int rt = pass * 3 + rt3;
            #pragma unroll
            for (int ct = 0; ct < 4; ++ct) {
                int p = wv * 64 + ct * 16 + col16;
                #pragma unroll
                for (int rr = 0; rr < 4; ++rr) {
                    int m = rt * 16 + g * 4 + rr;
                    h_s[(rt3 * 16 + g * 4 + rr) * 264 + p] =
                        (_Float16)fmaf(acc[rt][ct][rr], s3[m], b3f[m]);
                }
            }
        }
        __syncthreads();
        #pragma unroll
        for (int i = 0; i < 6; ++i) {
            int flat = i * 2048 + t * 8;        // covers 48*256
            int mL = flat >> 8;
            int p = flat & 255;
            f16x8 hv = *(const f16x8*)(h_s + mL * 264 + p);
            int m = pass * 48 + mL;
            int row = y0 + (p >> 6);
            int colg = x0 + (p & 63);
            *(f16x8*)(h_out + ((long)(b * CINC + m)) * HW + (long)row * WID + colg) = hv;

            float s = 0.f;
            if (!(x0 == 48 && (p & 63) < 16)) {  // overlap cols 48..63 counted by half-0
                #pragma unroll
                for (int e = 0; e < 8; ++e) s += (float)hv[e];
            }
            s += __shfl_xor(s, 1);
            s += __shfl_xor(s, 2);
            s += __shfl_xor(s, 4);
            s += __shfl_xor(s, 8);
            s += __shfl_xor(s, 16);
            if ((lane & 31) == 0) atomicAdd(&ssum[m], s);
        }
        __syncthreads();
    }
    if (t < CINC) atomicAdd(&sums[b * CINC + t], ssum[t]);
}

// ---------------- gates: mean(h) -> fc1+relu -> fc2 -> hardsig -> a1,b1 -------
__global__ __launch_bounds__(192) void k_gates(const float* __restrict__ sums,
                                               const float* __restrict__ fc1w,
                                               const float* __restrict__ fc1b,
                                               const float* __restrict__ fc2w,
                                               const float* __restrict__ fc2b,
                                               float* __restrict__ a1b1)
{
    __shared__ float mean_s[CINC];
    __shared__ float mid[24];
    int b = blockIdx.x;
    int t = threadIdx.x;     // 192

    if (t < CINC) mean_s[t] = sums[b * CINC + t] * (1.0f / 12544.0f);
    __syncthreads();
    if (t < 24) {
        float d = fc1b[t];
        #pragma unroll 4
        for (int c = 0; c < CINC; ++c) d = fmaf(fc1w[t * CINC + c], mean_s[c], d);
        mid[t] = fmaxf(d, 0.f);
    }
    __syncthreads();
    {
        float d = fc2b[t];
        #pragma unroll
        for (int j = 0; j < 24; ++j) d = fmaf(fc2w[t * 24 + j], mid[j], d);
        float y = fminf(fmaxf(d + 3.f, 0.f), 6.f) * (1.f / 6.f);
        y = (y - 0.5f) * 4.f;
        a1b1[b * 192 + t] = (t < CINC) ? (y + 1.f) : y;
    }
}

// ---------------- final: h*a1 + roll(h)*b1, shuffle(48), + x (pure streaming) --
__global__ __launch_bounds__(256) void k_final(const _Float16* __restrict__ h,
                                               const float* __restrict__ xin,
                                               const float* __restrict__ a1b1,
                                               float* __restrict__ out)
{
    int q = blockIdx.x * 256 + threadIdx.x;      // 4,816,896 quads total (exact)
    int pos4 = q % 3136;
    int bo = q / 3136;
    int o = bo % CINC, b = bo / CINC;
    int c = (o % 48) * 2 + (o / 48);             // shuffle(48) folded
    int cn = (c + 1) % CINC;                      // channel roll

    float av = a1b1[b * 192 + c];
    float bv = a1b1[b * 192 + 96 + c];

    long hb = (long)b * CINC * HW;
    f16x4 hv4 = *(const f16x4*)(h + hb + (long)c  * HW + pos4 * 4);
    f16x4 h2v = *(const f16x4*)(h + hb + (long)cn * HW + pos4 * 4);

    long xo = ((long)(b * CINC + o)) * HW + pos4 * 4;
    f32x4 xv = *(const f32x4*)(xin + xo);
    f32x4 rr;
    #pragma unroll
    for (int j = 0; j < 4; ++j)
        rr[j] = fmaf((float)hv4[j], av, fmaf((float)h2v[j], bv, xv[j]));
    *(f32x4*)(out + xo) = rr;
}

extern "C" void kernel_launch(void* const* d_in, const int* in_sizes, int n_in,
                              void* d_out, int out_size, void* d_ws, size_t ws_size,
                              hipStream_t stream)
{
    const float* x    = (const float*)d_in[0];
    const float* wdw1 = (const float*)d_in[1];
    const float* g1   = (const float*)d_in[2];
    const float* b1   = (const float*)d_in[3];
    const float* m1   = (const float*)d_in[4];
    const float* v1   = (const float*)d_in[5];
    const float* wdw2 = (const float*)d_in[6];
    const float* g2   = (const float*)d_in[7];
    const float* b2   = (const float*)d_in[8];
    const float* m2   = (const float*)d_in[9];
    const float* v2   = (const float*)d_in[10];
    const float* wpw  = (const float*)d_in[11];
    const float* g3   = (const float*)d_in[12];
    const float* b3   = (const float*)d_in[13];
    const float* m3   = (const float*)d_in[14];
    const float* v3   = (const float*)d_in[15];
    const float* fc1w = (const float*)d_in[16];
    const float* fc1b = (const float*)d_in[17];
    const float* fc2w = (const float*)d_in[18];
    const float* fc2b = (const float*)d_in[19];

    float* ws   = (float*)d_ws;
    float* sums = ws + WS_S;
    float* a1b1 = ws + WS_A1B1;
    _Float16* hbuf = (_Float16*)((char*)d_ws + WS_H_BYTES);
    float* out  = (float*)d_out;

    hipMemsetAsync(sums, 0, 1536 * sizeof(float), stream);
    k_prep<<<dim3(40), dim3(256), 0, stream>>>(
        wdw1, g1, b1, m1, v1, wdw2, g2, b2, m2, v2,
        wpw, g3, b3, m3, v3, ws);
    k_main7<<<dim3(896), dim3(256), 0, stream>>>(x, ws, sums, hbuf);
    k_gates<<<dim3(BATCH), dim3(192), 0, stream>>>(sums, fc1w, fc1b, fc2w, fc2b, a1b1);
    k_final<<<dim3(4816896 / 256), dim3(256), 0, stream>>>(hbuf, x, a1b1, out);
}

// Round 14
// 119.191 us; speedup vs baseline: 4.4703x; 4.4703x over previous
//
#include <hip/hip_runtime.h>
#include <hip/hip_bf16.h>

#define BATCH 16
#define CINC 96
#define HGT 112
#define WID 112
#define HW 12544          // 112*112
#define C1N 192
#define C2N 384
#define EPSV 1e-5f

typedef _Float16 f16x8 __attribute__((ext_vector_type(8)));
typedef _Float16 f16x4 __attribute__((ext_vector_type(4)));
typedef float    f32x4 __attribute__((ext_vector_type(4)));

// d_ws layout (float offsets unless noted)
#define WS_S      0        // 16*96 f32 h-sums (zeroed each launch)
#define WS_A1B1   1536     // 16*192 f32
#define WS_W1F    4608     // 192*3
#define WS_B1F    5184     // 192
#define WS_W2F    5376     // 384*3
#define WS_B2F    6528     // 384
#define WS_S3     6912     // 96
#define WS_B3     7008     // 96
#define WS_WPF_BYTES (7104*4)                    // f16 wpf[chunk][ks][rt][lane][8]
#define WS_H_BYTES   (WS_WPF_BYTES + CINC*C2N*2) // f16 h[16][96][12544] = 38.5 MB

// ---------------- prep: fold BN into weights; Wp -> chunk-contiguous fragments --
// wpf[(((ksg)*6+rt)*64+lane)*8+e] = Wp[rt*16+(lane&15)][ksg*32+(lane>>4)*8+e]
// Wp[m][k] = w_pw[m][(k%64)*6 + k/64]  (channel shuffle groups=6 folded)
__global__ void k_prep(const float* __restrict__ wdw1, const float* __restrict__ g1,
                       const float* __restrict__ bb1, const float* __restrict__ m1,
                       const float* __restrict__ v1,
                       const float* __restrict__ wdw2, const float* __restrict__ g2,
                       const float* __restrict__ bb2, const float* __restrict__ m2,
                       const float* __restrict__ v2,
                       const float* __restrict__ wpw, const float* __restrict__ g3,
                       const float* __restrict__ bb3, const float* __restrict__ m3,
                       const float* __restrict__ v3,
                       float* ws)
{
    int t = blockIdx.x * blockDim.x + threadIdx.x;
    int stride = gridDim.x * blockDim.x;
    float* w1f = ws + WS_W1F; float* b1f = ws + WS_B1F;
    float* w2f = ws + WS_W2F; float* b2f = ws + WS_B2F;
    float* s3  = ws + WS_S3;  float* b3f = ws + WS_B3;
    _Float16* wpf = (_Float16*)((char*)ws + WS_WPF_BYTES);

    for (int c = t; c < C1N; c += stride) {
        float s = g1[c] / sqrtf(v1[c] + EPSV);
        w1f[c*3+0] = wdw1[c*3+0] * s;
        w1f[c*3+1] = wdw1[c*3+1] * s;
        w1f[c*3+2] = wdw1[c*3+2] * s;
        b1f[c] = bb1[c] - m1[c] * s;
    }
    for (int c = t; c < C2N; c += stride) {
        float s = g2[c] / sqrtf(v2[c] + EPSV);
        w2f[c*3+0] = wdw2[c*3+0] * s;
        w2f[c*3+1] = wdw2[c*3+1] * s;
        w2f[c*3+2] = wdw2[c*3+2] * s;
        b2f[c] = bb2[c] - m2[c] * s;
    }
    for (int c = t; c < CINC; c += stride) {
        float s = g3[c] / sqrtf(v3[c] + EPSV);
        s3[c] = s; b3f[c] = bb3[c] - m3[c] * s;
    }
    for (int idx = t; idx < CINC * C2N; idx += stride) {
        int e = idx & 7;
        int l2 = idx >> 3;
        int lane = l2 & 63;
        int l3 = l2 >> 6;
        int rt = l3 % 6, ksg = l3 / 6;
        int m = rt * 16 + (lane & 15);
        int k = ksg * 32 + (lane >> 4) * 8 + e;
        int o = (k & 63) * 6 + (k >> 6);
        wpf[idx] = (_Float16)wpw[m * C2N + o];
    }
}

// x-data for one channel pair
struct PairX {
    f32x4 T[2], M[2], B[2];
    float eT[2], eM[2], eB[2];
};

// ---------------- main: preload-pipelined dw -> LDS Wp MFMA -> h+sums ----------
// block = 4 rows x 64 cols; thread = (row r, 4-col c4); 72 KB LDS -> 2 blk/CU
__global__ __launch_bounds__(256, 2) void k_main8(const float* __restrict__ x,
                                                  const float* __restrict__ ws,
                                                  float* __restrict__ sums,
                                                  _Float16* __restrict__ h_out)
{
    __shared__ __align__(16) char u_raw[256 * 208];   // u tile (slot-rotated); h_s aliases
    __shared__ __align__(16) f16x8 wpf_s[1152];       // Wp chunk fragments (18432 B)
    __shared__ float ssum[CINC];

    int t   = threadIdx.x;
    int bid = blockIdx.x;
    int logical = (bid & 7) * 112 + (bid >> 3);       // XCD-chunked (896 = 8*112)
    int b   = logical / 56;
    int rem = logical - b * 56;
    int y0  = (rem >> 1) * 4;
    int x0  = (rem & 1) * 48;

    int wv = t >> 6, lane = t & 63;
    int r = lane >> 4, c4 = lane & 15;
    int gy = y0 + r;
    int gc = x0 + 4 * c4;
    int col16 = c4, g = r;                            // MFMA-phase aliases

    const float* w1f = ws + WS_W1F; const float* b1f = ws + WS_B1F;
    const float* w2f = ws + WS_W2F; const float* b2f = ws + WS_B2F;

    if (t < CINC) ssum[t] = 0.f;

    bool ymok = gy >= 1;
    bool ypok = gy + 1 < HGT;
    bool isE  = (c4 == 0) | (c4 == 15);
    int  ecol = (c4 == 0) ? (x0 - 1) : (x0 + 64);
    bool ev   = isE && ((unsigned)ecol < (unsigned)WID);
    int  secol = ev ? ecol : 0;
    int  tm = ymok ? -WID : 0;
    int  tp = ypok ?  WID : 0;

    f32x4 acc[6][4];
    #pragma unroll
    for (int rt = 0; rt < 6; ++rt)
        #pragma unroll
        for (int ct = 0; ct < 4; ++ct) acc[rt][ct] = (f32x4){0.f, 0.f, 0.f, 0.f};

    const f16x8* wpf_g = (const f16x8*)((const char*)ws + WS_WPF_BYTES);
    long xb = (long)b * CINC * HW;
    const float* xw = x + xb + (long)gy * WID;        // + cu*HW + col

    int rotbase = 3 * r + c4;
    char* ub0 = u_raw + (r * 64 + 4 * c4) * 208;

    // prefetch chunk 0's Wp fragments into registers
    f16x8 nw0 = wpf_g[t];
    f16x8 nw1 = wpf_g[256 + t];
    f16x8 nw2 = wpf_g[512 + t];
    f16x8 nw3 = wpf_g[768 + t];
    f16x8 nw4 = nw0;
    if (t < 128) nw4 = wpf_g[1024 + t];

    #define LOADCH(dst, q, cuq) {                                         \
        const float* p_ = xw + (long)(cuq) * HW;                          \
        (dst).M[q] = *(const f32x4*)(p_ + gc);                            \
        (dst).T[q] = *(const f32x4*)(p_ + gc + tm);                       \
        (dst).B[q] = *(const f32x4*)(p_ + gc + tp);                       \
        if (isE) {                                                        \
            const float* e_ = p_ + secol;                                 \
            (dst).eM[q] = e_[0]; (dst).eT[q] = e_[tm]; (dst).eB[q] = e_[tp]; \
        } }

    for (int chunk = 0; chunk < 4; ++chunk) {
        if (chunk) __syncthreads();       // prev MFMA reads done before overwrite

        // stage Wp fragments from prefetch regs (pure ds_write, no global wait)
        wpf_s[t] = nw0;
        wpf_s[256 + t] = nw1;
        wpf_s[512 + t] = nw2;
        wpf_s[768 + t] = nw3;
        if (t < 128) wpf_s[1024 + t] = nw4;

        int cbase = chunk * 24 + wv * 6;
        PairX A, B;
        LOADCH(A, 0, cbase + 0)
        LOADCH(A, 1, cbase + 1)

        // 3 pairs, software-pipelined: load pair p+1 while computing pair p
        #pragma unroll
        for (int p = 0; p < 3; ++p) {
            if (p == 0) { LOADCH(B, 0, cbase + 2) LOADCH(B, 1, cbase + 3) }
            if (p == 1) { LOADCH(A, 0, cbase + 4) LOADCH(A, 1, cbase + 5) }
            PairX& C = (p == 1) ? B : A;

            f16x4 uv[2][4];
            #pragma unroll
            for (int q = 0; q < 2; ++q) {
                int cu = cbase + 2 * p + q;
                int c1a = cu * 2;
                float wa0 = w1f[c1a*3+0], wa1 = w1f[c1a*3+1], wa2 = w1f[c1a*3+2], ba = b1f[c1a];
                float wb0 = w1f[c1a*3+3], wb1 = w1f[c1a*3+4], wb2 = w1f[c1a*3+5], bb = b1f[c1a+1];

                float va[4], vb[4];
                #pragma unroll
                for (int j = 0; j < 4; ++j) {
                    float tt = ymok ? C.T[q][j] : 0.f;
                    float bt = ypok ? C.B[q][j] : 0.f;
                    va[j] = fmaf(wa0, tt, fmaf(wa1, C.M[q][j], fmaf(wa2, bt, ba)));
                    vb[j] = fmaf(wb0, tt, fmaf(wb1, C.M[q][j], fmaf(wb2, bt, bb)));
                }
                // conv2 zero-pads BN1 output: out-of-image edge column -> 0
                float etS = (ymok && ev) ? C.eT[q] : 0.f;
                float ebS = (ypok && ev) ? C.eB[q] : 0.f;
                float emS = ev ? C.eM[q] : 0.f;
                float vea = ev ? fmaf(wa0, etS, fmaf(wa1, emS, fmaf(wa2, ebS, ba))) : 0.f;
                float veb = ev ? fmaf(wb0, etS, fmaf(wb1, emS, fmaf(wb2, ebS, bb))) : 0.f;

                float vLa = __shfl(va[3], (lane + 63) & 63);
                float vLb = __shfl(vb[3], (lane + 63) & 63);
                float vRa = __shfl(va[0], (lane + 1) & 63);
                float vRb = __shfl(vb[0], (lane + 1) & 63);
                if (c4 == 0)  { vLa = vea; vLb = veb; }
                if (c4 == 15) { vRa = vea; vRb = veb; }

                int c2b = cu * 4;
                float pa[6] = {vLa, va[0], va[1], va[2], va[3], vRa};
                float pb[6] = {vLb, vb[0], vb[1], vb[2], vb[3], vRb};
                #pragma unroll
                for (int j = 0; j < 4; ++j) {
                    #pragma unroll
                    for (int jj = 0; jj < 4; ++jj) {
                        float p0 = (jj < 2) ? pa[j]     : pb[j];
                        float p1 = (jj < 2) ? pa[j + 1] : pb[j + 1];
                        float p2 = (jj < 2) ? pa[j + 2] : pb[j + 2];
                        float tv = fmaf(w2f[(c2b+jj)*3+0], p0,
                                   fmaf(w2f[(c2b+jj)*3+1], p1,
                                   fmaf(w2f[(c2b+jj)*3+2], p2, b2f[c2b+jj])));
                        uv[q][j][jj] = (_Float16)fminf(fmaxf(tv, 0.f), 6.f);
                    }
                }
            }
            // paired 16-B store: k-cell = wv*3+p, rotated
            int slot = (wv * 3 + p + rotbase) % 12;
            char* ubase = ub0 + slot * 16;
            #pragma unroll
            for (int j = 0; j < 4; ++j) {
                f16x8 w = __builtin_shufflevector(uv[0][j], uv[1][j], 0, 1, 2, 3, 4, 5, 6, 7);
                *(f16x8*)(ubase + j * 208) = w;
            }
        }

        // prefetch next chunk's Wp during barrier + MFMA
        if (chunk < 3) {
            int cb = (chunk + 1) * 1152;
            nw0 = wpf_g[cb + t];
            nw1 = wpf_g[cb + 256 + t];
            nw2 = wpf_g[cb + 512 + t];
            nw3 = wpf_g[cb + 768 + t];
            if (t < 128) nw4 = wpf_g[cb + 1024 + t];
        }
        __syncthreads();   // u + wpf_s ready

        // MFMA: acc += Wp[:, chunk slice] * u  (all operands in LDS)
        #pragma unroll
        for (int ks = 0; ks < 3; ++ks) {
            f16x8 bfr[4];
            #pragma unroll
            for (int ct = 0; ct < 4; ++ct) {
                int pos = wv * 64 + ct * 16 + col16;
                int sl = (ks * 4 + g + 3 * wv + ((pos >> 2) & 15)) % 12;
                bfr[ct] = *(const f16x8*)(u_raw + pos * 208 + sl * 16);
            }
            #pragma unroll
            for (int rt = 0; rt < 6; ++rt) {
                f16x8 afr = wpf_s[(ks * 6 + rt) * 64 + lane];
                #pragma unroll
                for (int ct = 0; ct < 4; ++ct)
                    acc[rt][ct] = __builtin_amdgcn_mfma_f32_16x16x32_f16(afr, bfr[ct], acc[rt][ct], 0, 0, 0);
            }
        }
    }
    __syncthreads();   // last MFMA reads done before aliasing u_raw with h

    // stage h (bn3, f16) into LDS: h_s[m][264]
    _Float16* h_s = (_Float16*)u_raw;
    const float* s3  = ws + WS_S3;
    const float* b3f = ws + WS_B3;
    #pragma unroll
    for (int rt = 0; rt < 6; ++rt) {
        #pragma unroll
        for (int ct = 0; ct < 4; ++ct) {
            int p = wv * 64 + ct * 16 + col16;
            #pragma unroll
            for (int rr = 0; rr < 4; ++rr) {
                int m = rt * 16 + g * 4 + rr;
                h_s[m * 264 + p] = (_Float16)fmaf(acc[rt][ct][rr], s3[m], b3f[m]);
            }
        }
    }
    __syncthreads();

    // coalesced full-line h stores + channel sums (overlap cols masked)
    #pragma unroll
    for (int i = 0; i < 12; ++i) {
        int flat = i * 2048 + t * 8;           // covers 96*256 exactly
        int m = flat >> 8;
        int p = flat & 255;
        f16x8 hv = *(const f16x8*)(h_s + m * 264 + p);
        int row = y0 + (p >> 6);
        int colg = x0 + (p & 63);
        *(f16x8*)(h_out + ((long)(b * CINC + m)) * HW + (long)row * WID + colg) = hv;

        float s = 0.f;
        if (!(x0 == 48 && (p & 63) < 16)) {    // overlap cols 48..63 counted by half-0
            #pragma unroll
            for (int e = 0; e < 8; ++e) s += (float)hv[e];
        }
        s += __shfl_xor(s, 1);
        s += __shfl_xor(s, 2);
        s += __shfl_xor(s, 4);
        s += __shfl_xor(s, 8);
        s += __shfl_xor(s, 16);
        if ((lane & 31) == 0) atomicAdd(&ssum[m], s);
    }
    __syncthreads();
    if (t < CINC) atomicAdd(&sums[b * CINC + t], ssum[t]);
}

// ---------------- gates: mean(h) -> fc1+relu -> fc2 -> hardsig -> a1,b1 -------
__global__ __launch_bounds__(192) void k_gates(const float* __restrict__ sums,
                                               const float* __restrict__ fc1w,
                                               const float* __restrict__ fc1b,
                                               const float* __restrict__ fc2w,
                                               const float* __restrict__ fc2b,
                                               float* __restrict__ a1b1)
{
    __shared__ float mean_s[CINC];
    __shared__ float mid[24];
    int b = blockIdx.x;
    int t = threadIdx.x;     // 192

    if (t < CINC) mean_s[t] = sums[b * CINC + t] * (1.0f / 12544.0f);
    __syncthreads();
    if (t < 24) {
        float d = fc1b[t];
        #pragma unroll 4
        for (int c = 0; c < CINC; ++c) d = fmaf(fc1w[t * CINC + c], mean_s[c], d);
        mid[t] = fmaxf(d, 0.f);
    }
    __syncthreads();
    {
        float d = fc2b[t];
        #pragma unroll
        for (int j = 0; j < 24; ++j) d = fmaf(fc2w[t * 24 + j], mid[j], d);
        float y = fminf(fmaxf(d + 3.f, 0.f), 6.f) * (1.f / 6.f);
        y = (y - 0.5f) * 4.f;
        a1b1[b * 192 + t] = (t < CINC) ? (y + 1.f) : y;
    }
}

// ---------------- final: h*a1 + roll(h)*b1, shuffle(48), + x (pure streaming) --
__global__ __launch_bounds__(256) void k_final(const _Float16* __restrict__ h,
                                               const float* __restrict__ xin,
                                               const float* __restrict__ a1b1,
                                               float* __restrict__ out)
{
    int q = blockIdx.x * 256 + threadIdx.x;      // 4,816,896 quads total (exact)
    int pos4 = q % 3136;
    int bo = q / 3136;
    int o = bo % CINC, b = bo / CINC;
    int c = (o % 48) * 2 + (o / 48);             // shuffle(48) folded
    int cn = (c + 1) % CINC;                      // channel roll

    float av = a1b1[b * 192 + c];
    float bv = a1b1[b * 192 + 96 + c];

    long hb = (long)b * CINC * HW;
    f16x4 hv4 = *(const f16x4*)(h + hb + (long)c  * HW + pos4 * 4);
    f16x4 h2v = *(const f16x4*)(h + hb + (long)cn * HW + pos4 * 4);

    long xo = ((long)(b * CINC + o)) * HW + pos4 * 4;
    f32x4 xv = *(const f32x4*)(xin + xo);
    f32x4 rr;
    #pragma unroll
    for (int j = 0; j < 4; ++j)
        rr[j] = fmaf((float)hv4[j], av, fmaf((float)h2v[j], bv, xv[j]));
    *(f32x4*)(out + xo) = rr;
}

extern "C" void kernel_launch(void* const* d_in, const int* in_sizes, int n_in,
                              void* d_out, int out_size, void* d_ws, size_t ws_size,
                              hipStream_t stream)
{
    const float* x    = (const float*)d_in[0];
    const float* wdw1 = (const float*)d_in[1];
    const float* g1   = (const float*)d_in[2];
    const float* b1   = (const float*)d_in[3];
    const float* m1   = (const float*)d_in[4];
    const float* v1   = (const float*)d_in[5];
    const float* wdw2 = (const float*)d_in[6];
    const float* g2   = (const float*)d_in[7];
    const float* b2   = (const float*)d_in[8];
    const float* m2   = (const float*)d_in[9];
    const float* v2   = (const float*)d_in[10];
    const float* wpw  = (const float*)d_in[11];
    const float* g3   = (const float*)d_in[12];
    const float* b3   = (const float*)d_in[13];
    const float* m3   = (const float*)d_in[14];
    const float* v3   = (const float*)d_in[15];
    const float* fc1w = (const float*)d_in[16];
    const float* fc1b = (const float*)d_in[17];
    const float* fc2w = (const float*)d_in[18];
    const float* fc2b = (const float*)d_in[19];

    float* ws   = (float*)d_ws;
    float* sums = ws + WS_S;
    float* a1b1 = ws + WS_A1B1;
    _Float16* hbuf = (_Float16*)((char*)d_ws + WS_H_BYTES);
    float* out  = (float*)d_out;

    hipMemsetAsync(sums, 0, 1536 * sizeof(float), stream);
    k_prep<<<dim3(40), dim3(256), 0, stream>>>(
        wdw1, g1, b1, m1, v1, wdw2, g2, b2, m2, v2,
        wpw, g3, b3, m3, v3, ws);
    k_main8<<<dim3(896), dim3(256), 0, stream>>>(x, ws, sums, hbuf);
    k_gates<<<dim3(BATCH), dim3(192), 0, stream>>>(sums, fc1w, fc1b, fc2w, fc2b, a1b1);
    k_final<<<dim3(4816896 / 256), dim3(256), 0, stream>>>(hbuf, x, a1b1, out);
}